// Round 1
// baseline (244.035 us; speedup 1.0000x reference)
//
#include <hip/hip_runtime.h>
#include <hip/hip_bf16.h>

#define NHALF 4096
#define TWO_N 8192
#define DDIM 256
#define INV_T 10.0f
// 10 * log2(e): exp(s) = exp2(s * SCALE) where s is the raw dot (pre 1/T)
#define SCALE 14.426950408889634f

typedef __bf16 v8bf __attribute__((ext_vector_type(8)));
typedef float f32x4 __attribute__((ext_vector_type(4)));

// ---------------- kernel 1: normalize rows, emit bf16 zn ----------------
__global__ __launch_bounds__(256) void ntx_norm_kernel(
    const float* __restrict__ zi, const float* __restrict__ zj,
    __hip_bfloat16* __restrict__ zn) {
    const int r = blockIdx.x;
    const int d = threadIdx.x;
    const float* src = (r < NHALF) ? (zi + (size_t)r * DDIM)
                                   : (zj + (size_t)(r - NHALF) * DDIM);
    float x = src[d];
    __shared__ float red[256];
    __shared__ float rinv_s;
    red[d] = x * x;
    __syncthreads();
    for (int s = 128; s > 0; s >>= 1) {
        if (d < s) red[d] += red[d + s];
        __syncthreads();
    }
    if (d == 0) {
        float nrm = fmaxf(sqrtf(red[0]), 1e-8f);
        rinv_s = 1.0f / nrm;
    }
    __syncthreads();
    zn[(size_t)r * DDIM + d] = __float2bfloat16(x * rinv_s);
}

// ---------------- kernel 2: Gram + partial sum-of-exp ----------------
// grid = 128 row-tiles(64 rows) x 4 col-quarters(2048 cols) = 512 blocks.
// 4 waves/block; wave w owns rows [rtile*64 + 16w, +16), sweeps its quarter.
__global__ __launch_bounds__(256) void ntx_gram_kernel(
    const __hip_bfloat16* __restrict__ zn,
    float* __restrict__ partial,   // [4][TWO_N]
    float* __restrict__ spos) {    // [TWO_N]
    const int b = blockIdx.x;
    const int rtile = b >> 2;          // 0..127
    const int q = b & 3;               // col quarter
    const int w = threadIdx.x >> 6;    // wave 0..3
    const int lane = threadIdx.x & 63;
    const int wrbase = rtile * 64 + w * 16;

    const int lrow = lane & 15;        // row (for A) / col (for B, C/D)
    const int lk = lane >> 4;          // k-group 0..3

    const char* znb = (const char*)zn; // row stride = 512 B

    // A fragments: zn[wrbase + lrow][kb*32 + lk*8 .. +7]
    const char* abase = znb + (((size_t)(wrbase + lrow)) << 9) + (lk << 4);
    v8bf afrag[8];
#pragma unroll
    for (int kb = 0; kb < 8; ++kb)
        afrag[kb] = *(const v8bf*)(abase + kb * 64);

    const int cq0 = q * 2048;
    const bool has_diag = (wrbase >= cq0) && (wrbase < cq0 + 2048);
    const int diag_t = (wrbase - cq0) >> 4;
    const int pcol = (wrbase + NHALF) & (TWO_N - 1);
    const bool has_pos = (pcol >= cq0) && (pcol < cq0 + 2048);
    const int pos_t = (pcol - cq0) >> 4;

    float sume[4] = {0.f, 0.f, 0.f, 0.f};

    for (int t = 0; t < 128; ++t) {
        const int cbase = cq0 + t * 16;
        const char* bbase = znb + (((size_t)(cbase + lrow)) << 9) + (lk << 4);
        f32x4 acc = {0.f, 0.f, 0.f, 0.f};
#pragma unroll
        for (int kb = 0; kb < 8; ++kb) {
            v8bf bfrag = *(const v8bf*)(bbase + kb * 64);
            acc = __builtin_amdgcn_mfma_f32_16x16x32_bf16(afrag[kb], bfrag, acc, 0, 0, 0);
        }
        const bool isdiag_tile = has_diag && (t == diag_t);
        const bool ispos_tile = has_pos && (t == pos_t);
#pragma unroll
        for (int j = 0; j < 4; ++j) {
            const int row = lk * 4 + j;        // row within tile (C/D layout)
            const bool ondiag = (lrow == row); // col == row within tile
            float s = acc[j];
            if (ispos_tile && ondiag) spos[wrbase + row] = s * INV_T;
            float e = exp2f(s * SCALE);
            sume[j] += (isdiag_tile && ondiag) ? 0.f : e;
        }
    }

    // reduce across the 16 columns (lanes sharing lk differ in bits 0..3)
#pragma unroll
    for (int j = 0; j < 4; ++j) {
        float v = sume[j];
        v += __shfl_xor(v, 1);
        v += __shfl_xor(v, 2);
        v += __shfl_xor(v, 4);
        v += __shfl_xor(v, 8);
        sume[j] = v;
    }
    if (lrow == 0) {
#pragma unroll
        for (int j = 0; j < 4; ++j)
            partial[(size_t)q * TWO_N + wrbase + lk * 4 + j] = sume[j];
    }
}

// ---------------- kernel 3: finalize ----------------
__global__ __launch_bounds__(1024) void ntx_final_kernel(
    const float* __restrict__ partial, const float* __restrict__ spos,
    float* __restrict__ out) {
    const int tid = threadIdx.x;
    float lsum = 0.f;
    for (int r = tid; r < TWO_N; r += 1024) {
        float se = partial[r] + partial[TWO_N + r] + partial[2 * TWO_N + r] +
                   partial[3 * TWO_N + r];
        lsum += logf(se) - spos[r];
    }
    __shared__ float red[1024];
    red[tid] = lsum;
    __syncthreads();
    for (int s = 512; s > 0; s >>= 1) {
        if (tid < s) red[tid] += red[tid + s];
        __syncthreads();
    }
    if (tid == 0) out[0] = red[0] / (float)TWO_N;
}

extern "C" void kernel_launch(void* const* d_in, const int* in_sizes, int n_in,
                              void* d_out, int out_size, void* d_ws, size_t ws_size,
                              hipStream_t stream) {
    const float* zi = (const float*)d_in[0];
    const float* zj = (const float*)d_in[1];
    char* ws = (char*)d_ws;
    __hip_bfloat16* zn = (__hip_bfloat16*)ws;                        // 4 MB
    float* partial = (float*)(ws + (size_t)TWO_N * DDIM * 2);        // 128 KB
    float* spos = (float*)(ws + (size_t)TWO_N * DDIM * 2 + (size_t)4 * TWO_N * 4);
    float* out = (float*)d_out;

    ntx_norm_kernel<<<TWO_N, 256, 0, stream>>>(zi, zj, zn);
    ntx_gram_kernel<<<512, 256, 0, stream>>>(zn, partial, spos);
    ntx_final_kernel<<<1, 1024, 0, stream>>>(partial, spos, out);
}

// Round 2
// 243.885 us; speedup vs baseline: 1.0006x; 1.0006x over previous
//
#include <hip/hip_runtime.h>
#include <hip/hip_bf16.h>

#define NHALF 4096
#define TWO_N 8192
#define DDIM 256
#define INV_T 10.0f
// 10 * log2(e): exp(s) = exp2(s * SCALE) where s is the raw dot (pre 1/T)
#define SCALE 14.426950408889634f

typedef __bf16 v8bf __attribute__((ext_vector_type(8)));
typedef float f32x4 __attribute__((ext_vector_type(4)));

// ---------------- kernel 1: normalize rows, emit bf16 zn ----------------
__global__ __launch_bounds__(256) void ntx_norm_kernel(
    const float* __restrict__ zi, const float* __restrict__ zj,
    __hip_bfloat16* __restrict__ zn) {
    const int r = blockIdx.x;
    const int d = threadIdx.x;
    const float* src = (r < NHALF) ? (zi + (size_t)r * DDIM)
                                   : (zj + (size_t)(r - NHALF) * DDIM);
    float x = src[d];
    __shared__ float red[256];
    __shared__ float rinv_s;
    red[d] = x * x;
    __syncthreads();
    for (int s = 128; s > 0; s >>= 1) {
        if (d < s) red[d] += red[d + s];
        __syncthreads();
    }
    if (d == 0) {
        float nrm = fmaxf(sqrtf(red[0]), 1e-8f);
        rinv_s = 1.0f / nrm;
    }
    __syncthreads();
    zn[(size_t)r * DDIM + d] = __float2bfloat16(x * rinv_s);
}

// ---------------- kernel 2: Gram + partial sum-of-exp ----------------
// grid = 128 row-tiles(64 rows) x 4 col-quarters(2048 cols) = 512 blocks.
// 4 waves/block; wave w owns rows [rtile*64 + 16w, +16), sweeps its quarter.
__global__ __launch_bounds__(256) void ntx_gram_kernel(
    const __hip_bfloat16* __restrict__ zn,
    float* __restrict__ partial,   // [4][TWO_N]
    float* __restrict__ spos) {    // [TWO_N]
    const int b = blockIdx.x;
    const int rtile = b >> 2;          // 0..127
    const int q = b & 3;               // col quarter
    const int w = threadIdx.x >> 6;    // wave 0..3
    const int lane = threadIdx.x & 63;
    const int wrbase = rtile * 64 + w * 16;

    const int lrow = lane & 15;        // row (for A) / col (for B, C/D)
    const int lk = lane >> 4;          // k-group 0..3

    const char* znb = (const char*)zn; // row stride = 512 B

    // A fragments: zn[wrbase + lrow][kb*32 + lk*8 .. +7]
    const char* abase = znb + (((size_t)(wrbase + lrow)) << 9) + (lk << 4);
    v8bf afrag[8];
#pragma unroll
    for (int kb = 0; kb < 8; ++kb)
        afrag[kb] = *(const v8bf*)(abase + kb * 64);

    const int cq0 = q * 2048;
    const bool has_diag = (wrbase >= cq0) && (wrbase < cq0 + 2048);
    const int diag_t = (wrbase - cq0) >> 4;
    const int pcol = (wrbase + NHALF) & (TWO_N - 1);
    const bool has_pos = (pcol >= cq0) && (pcol < cq0 + 2048);
    const int pos_t = (pcol - cq0) >> 4;

    float sume[4] = {0.f, 0.f, 0.f, 0.f};

    for (int t = 0; t < 128; ++t) {
        const int cbase = cq0 + t * 16;
        const char* bbase = znb + (((size_t)(cbase + lrow)) << 9) + (lk << 4);
        f32x4 acc = {0.f, 0.f, 0.f, 0.f};
#pragma unroll
        for (int kb = 0; kb < 8; ++kb) {
            v8bf bfrag = *(const v8bf*)(bbase + kb * 64);
            acc = __builtin_amdgcn_mfma_f32_16x16x32_bf16(afrag[kb], bfrag, acc, 0, 0, 0);
        }
        const bool isdiag_tile = has_diag && (t == diag_t);
        const bool ispos_tile = has_pos && (t == pos_t);
#pragma unroll
        for (int j = 0; j < 4; ++j) {
            const int row = lk * 4 + j;        // row within tile (C/D layout)
            const bool ondiag = (lrow == row); // col == row within tile
            float s = acc[j];
            if (ispos_tile && ondiag) spos[wrbase + row] = s * INV_T;
            float e = exp2f(s * SCALE);
            sume[j] += (isdiag_tile && ondiag) ? 0.f : e;
        }
    }

    // reduce across the 16 columns (lanes sharing lk differ in bits 0..3)
#pragma unroll
    for (int j = 0; j < 4; ++j) {
        float v = sume[j];
        v += __shfl_xor(v, 1);
        v += __shfl_xor(v, 2);
        v += __shfl_xor(v, 4);
        v += __shfl_xor(v, 8);
        sume[j] = v;
    }
    if (lrow == 0) {
#pragma unroll
        for (int j = 0; j < 4; ++j)
            partial[(size_t)q * TWO_N + wrbase + lk * 4 + j] = sume[j];
    }
}

// ---------------- kernel 3: finalize ----------------
__global__ __launch_bounds__(1024) void ntx_final_kernel(
    const float* __restrict__ partial, const float* __restrict__ spos,
    float* __restrict__ out) {
    const int tid = threadIdx.x;
    float lsum = 0.f;
    for (int r = tid; r < TWO_N; r += 1024) {
        float se = partial[r] + partial[TWO_N + r] + partial[2 * TWO_N + r] +
                   partial[3 * TWO_N + r];
        lsum += logf(se) - spos[r];
    }
    __shared__ float red[1024];
    red[tid] = lsum;
    __syncthreads();
    for (int s = 512; s > 0; s >>= 1) {
        if (tid < s) red[tid] += red[tid + s];
        __syncthreads();
    }
    if (tid == 0) out[0] = red[0] / (float)TWO_N;
}

extern "C" void kernel_launch(void* const* d_in, const int* in_sizes, int n_in,
                              void* d_out, int out_size, void* d_ws, size_t ws_size,
                              hipStream_t stream) {
    const float* zi = (const float*)d_in[0];
    const float* zj = (const float*)d_in[1];
    char* ws = (char*)d_ws;
    __hip_bfloat16* zn = (__hip_bfloat16*)ws;                        // 4 MB
    float* partial = (float*)(ws + (size_t)TWO_N * DDIM * 2);        // 128 KB
    float* spos = (float*)(ws + (size_t)TWO_N * DDIM * 2 + (size_t)4 * TWO_N * 4);
    float* out = (float*)d_out;

    ntx_norm_kernel<<<TWO_N, 256, 0, stream>>>(zi, zj, zn);
    ntx_gram_kernel<<<512, 256, 0, stream>>>(zn, partial, spos);
    ntx_final_kernel<<<1, 1024, 0, stream>>>(partial, spos, out);
}

// Round 3
// 87.674 us; speedup vs baseline: 2.7834x; 2.7817x over previous
//
#include <hip/hip_runtime.h>
#include <hip/hip_bf16.h>

#define NHALF 4096
#define TWO_N 8192
#define DDIM 256
#define INV_T 10.0f
// 10 * log2(e): exp(10*s) = exp2(s * SCALE) where s is the raw cosine dot
#define SCALE 14.426950408889634f
#define NCHUNK 16   // column chunks of 512

typedef __bf16 v8bf __attribute__((ext_vector_type(8)));
typedef float f32x4 __attribute__((ext_vector_type(4)));

static __device__ __forceinline__ unsigned short f2bf(float x) {
    __hip_bfloat16 h = __float2bfloat16(x);
    return *(unsigned short*)&h;
}

// ---------------- kernel 1: normalize rows -> bf16 zn; also zero out ----------------
// one wave per row: lane loads float4 (16B), shfl-reduce sum of squares.
__global__ __launch_bounds__(256) void ntx_norm_kernel(
    const float* __restrict__ zi, const float* __restrict__ zj,
    __hip_bfloat16* __restrict__ zn, float* __restrict__ out) {
    const int w = threadIdx.x >> 6;
    const int lane = threadIdx.x & 63;
    const int r = blockIdx.x * 4 + w;
    const float* src = (r < NHALF) ? (zi + (size_t)r * DDIM)
                                   : (zj + (size_t)(r - NHALF) * DDIM);
    float4 v = ((const float4*)src)[lane];
    float ss = v.x * v.x + v.y * v.y + v.z * v.z + v.w * v.w;
#pragma unroll
    for (int m = 1; m < 64; m <<= 1) ss += __shfl_xor(ss, m);
    float rinv = 1.0f / fmaxf(sqrtf(ss), 1e-8f);
    ushort4 o;
    o.x = f2bf(v.x * rinv);
    o.y = f2bf(v.y * rinv);
    o.z = f2bf(v.z * rinv);
    o.w = f2bf(v.w * rinv);
    ((ushort4*)(zn + (size_t)r * DDIM))[lane] = o;
    if (blockIdx.x == 0 && threadIdx.x == 0) out[0] = 0.0f;
}

// ---------------- kernel 2: Gram + partial sum-of-exp ----------------
// grid = 32 row-blocks(256 rows) x 16 col-chunks(512 cols) = 512 blocks.
// 4 waves/block; wave w owns 64 rows (4 row-fragments of 16), A in registers.
// Per 16-col tile: 8 B-loads feed 32 MFMAs (4 independent acc chains).
__global__ __launch_bounds__(256) void ntx_gram_kernel(
    const __hip_bfloat16* __restrict__ zn,
    float* __restrict__ partial,   // [NCHUNK][TWO_N]
    float* __restrict__ spos) {    // [TWO_N]
    const int b = blockIdx.x;
    const int rblk = b >> 4;           // 0..31
    const int q = b & 15;              // col chunk 0..15
    const int w = threadIdx.x >> 6;    // wave 0..3
    const int lane = threadIdx.x & 63;
    const int wrbase = rblk * 256 + w * 64;   // wave's 64 rows

    const int lrow = lane & 15;        // row (A) / col (B, C/D)
    const int lk = lane >> 4;          // k-group 0..3

    const char* znb = (const char*)zn; // row stride = 512 B

    // A fragments for 4 row-tiles: zn[wrbase + rf*16 + lrow][kb*32 + lk*8 .. +7]
    v8bf afrag[4][8];
#pragma unroll
    for (int rf = 0; rf < 4; ++rf) {
        const char* abase =
            znb + (((size_t)(wrbase + rf * 16 + lrow)) << 9) + (lk << 4);
#pragma unroll
        for (int kb = 0; kb < 8; ++kb)
            afrag[rf][kb] = *(const v8bf*)(abase + kb * 64);
    }

    const int cq0 = q * 512;
    int dt[4], pt[4];
#pragma unroll
    for (int rf = 0; rf < 4; ++rf) {
        const int drow = wrbase + rf * 16;
        dt[rf] = (drow >= cq0 && drow < cq0 + 512) ? ((drow - cq0) >> 4) : -1;
        const int pcol = (drow + NHALF) & (TWO_N - 1);
        pt[rf] = (pcol >= cq0 && pcol < cq0 + 512) ? ((pcol - cq0) >> 4) : -1;
    }

    float sume[4][4];
#pragma unroll
    for (int rf = 0; rf < 4; ++rf)
#pragma unroll
        for (int j = 0; j < 4; ++j) sume[rf][j] = 0.0f;

    for (int t = 0; t < 32; ++t) {
        const char* bbase =
            znb + (((size_t)(cq0 + t * 16 + lrow)) << 9) + (lk << 4);
        v8bf bfrag[8];
#pragma unroll
        for (int kb = 0; kb < 8; ++kb)
            bfrag[kb] = *(const v8bf*)(bbase + kb * 64);

        f32x4 acc[4];
#pragma unroll
        for (int rf = 0; rf < 4; ++rf) acc[rf] = (f32x4){0.f, 0.f, 0.f, 0.f};
#pragma unroll
        for (int kb = 0; kb < 8; ++kb) {
#pragma unroll
            for (int rf = 0; rf < 4; ++rf)
                acc[rf] = __builtin_amdgcn_mfma_f32_16x16x32_bf16(
                    afrag[rf][kb], bfrag[kb], acc[rf], 0, 0, 0);
        }

#pragma unroll
        for (int rf = 0; rf < 4; ++rf) {
            const bool isd = (t == dt[rf]);   // wave-uniform
            const bool isp = (t == pt[rf]);   // wave-uniform
#pragma unroll
            for (int j = 0; j < 4; ++j) {
                const float s = acc[rf][j];
                const bool ondiag = (lrow == lk * 4 + j);
                if (isp && ondiag)
                    spos[wrbase + rf * 16 + lk * 4 + j] = s * INV_T;
                const float e = exp2f(s * SCALE);
                sume[rf][j] += (isd && ondiag) ? 0.0f : e;
            }
        }
    }

    // reduce across the 16 columns (lanes sharing lk differ in bits 0..3)
#pragma unroll
    for (int rf = 0; rf < 4; ++rf) {
#pragma unroll
        for (int j = 0; j < 4; ++j) {
            float v = sume[rf][j];
            v += __shfl_xor(v, 1);
            v += __shfl_xor(v, 2);
            v += __shfl_xor(v, 4);
            v += __shfl_xor(v, 8);
            if (lrow == 0)
                partial[(size_t)q * TWO_N + wrbase + rf * 16 + lk * 4 + j] = v;
        }
    }
}

// ---------------- kernel 3: finalize (out zeroed by kernel 1) ----------------
__global__ __launch_bounds__(256) void ntx_final_kernel(
    const float* __restrict__ partial, const float* __restrict__ spos,
    float* __restrict__ out) {
    const int tid = threadIdx.x;
    const int r = blockIdx.x * 256 + tid;
    float se = 0.0f;
#pragma unroll
    for (int c = 0; c < NCHUNK; ++c) se += partial[(size_t)c * TWO_N + r];
    float nll = logf(se) - spos[r];
    __shared__ float red[256];
    red[tid] = nll;
    __syncthreads();
    for (int s = 128; s > 0; s >>= 1) {
        if (tid < s) red[tid] += red[tid + s];
        __syncthreads();
    }
    if (tid == 0) atomicAdd(out, red[0] * (1.0f / (float)TWO_N));
}

extern "C" void kernel_launch(void* const* d_in, const int* in_sizes, int n_in,
                              void* d_out, int out_size, void* d_ws, size_t ws_size,
                              hipStream_t stream) {
    const float* zi = (const float*)d_in[0];
    const float* zj = (const float*)d_in[1];
    char* ws = (char*)d_ws;
    __hip_bfloat16* zn = (__hip_bfloat16*)ws;                          // 4 MB
    size_t off = (size_t)TWO_N * DDIM * 2;
    float* partial = (float*)(ws + off);                               // 512 KB
    off += (size_t)NCHUNK * TWO_N * 4;
    float* spos = (float*)(ws + off);                                  // 32 KB
    float* out = (float*)d_out;

    ntx_norm_kernel<<<TWO_N / 4, 256, 0, stream>>>(zi, zj, zn, out);
    ntx_gram_kernel<<<512, 256, 0, stream>>>(zn, partial, spos);
    ntx_final_kernel<<<TWO_N / 256, 256, 0, stream>>>(partial, spos, out);
}

// Round 4
// 81.993 us; speedup vs baseline: 2.9763x; 1.0693x over previous
//
#include <hip/hip_runtime.h>
#include <hip/hip_bf16.h>

#define NHALF 4096
#define TWO_N 8192
#define DDIM 256
#define INV_T 10.0f
// 10 * log2(e): exp(10*s) = exp2(s * SCALE) where s is the raw cosine dot
#define SCALE 14.426950408889634f
#define NCHUNK 16   // column chunks of 512

typedef __bf16 v8bf __attribute__((ext_vector_type(8)));
typedef float f32x4 __attribute__((ext_vector_type(4)));

#if __has_builtin(__builtin_amdgcn_exp2f)
#define EXP2F(x) __builtin_amdgcn_exp2f(x)
#else
#define EXP2F(x) exp2f(x)
#endif

static __device__ __forceinline__ unsigned short f2bf(float x) {
    __hip_bfloat16 h = __float2bfloat16(x);
    return *(unsigned short*)&h;
}

// ---------------- kernel 1: normalize rows -> bf16 zn; also zero out ----------------
__global__ __launch_bounds__(256) void ntx_norm_kernel(
    const float* __restrict__ zi, const float* __restrict__ zj,
    __hip_bfloat16* __restrict__ zn, float* __restrict__ out) {
    const int w = threadIdx.x >> 6;
    const int lane = threadIdx.x & 63;
    const int r = blockIdx.x * 4 + w;
    const float* src = (r < NHALF) ? (zi + (size_t)r * DDIM)
                                   : (zj + (size_t)(r - NHALF) * DDIM);
    float4 v = ((const float4*)src)[lane];
    float ss = v.x * v.x + v.y * v.y + v.z * v.z + v.w * v.w;
#pragma unroll
    for (int m = 1; m < 64; m <<= 1) ss += __shfl_xor(ss, m);
    float rinv = 1.0f / fmaxf(sqrtf(ss), 1e-8f);
    ushort4 o;
    o.x = f2bf(v.x * rinv);
    o.y = f2bf(v.y * rinv);
    o.z = f2bf(v.z * rinv);
    o.w = f2bf(v.w * rinv);
    ((ushort4*)(zn + (size_t)r * DDIM))[lane] = o;
    if (blockIdx.x == 0 && threadIdx.x == 0) out[0] = 0.0f;
}

// ---------------- kernel 2: Gram + partial sum-of-exp ----------------
// grid = 32 row-blocks(256 rows) x 16 col-chunks(512 cols) = 512 blocks.
// 4 waves/block; wave w owns 64 rows (4 row-fragments of 16), A in registers
// for the FULL k=256.  __launch_bounds__(256,2) -> 256-VGPR budget so the
// 128-VGPR afrag set stays resident (round-3 failure: default budget ~128
// caused per-tile spill/reload, VGPR_Count=104, ~440 VALU insts/tile).
__global__ __launch_bounds__(256, 2) void ntx_gram_kernel(
    const __hip_bfloat16* __restrict__ zn,
    float* __restrict__ partial,   // [NCHUNK][TWO_N]
    float* __restrict__ spos) {    // [TWO_N]
    const int b = blockIdx.x;
    const int rblk = b >> 4;           // 0..31
    const int q = b & 15;              // col chunk 0..15
    const int w = threadIdx.x >> 6;    // wave 0..3
    const int lane = threadIdx.x & 63;
    const int wrbase = rblk * 256 + w * 64;   // wave's 64 rows

    const int lrow = lane & 15;        // row (A) / col (B, C/D)
    const int lk = lane >> 4;          // k-group 0..3

    const char* znb = (const char*)zn; // row stride = 512 B

    // A fragments for 4 row-tiles: zn[wrbase + rf*16 + lrow][kb*32 + lk*8 .. +7]
    v8bf afrag[4][8];
#pragma unroll
    for (int rf = 0; rf < 4; ++rf) {
        const char* abase =
            znb + (((size_t)(wrbase + rf * 16 + lrow)) << 9) + (lk << 4);
#pragma unroll
        for (int kb = 0; kb < 8; ++kb)
            afrag[rf][kb] = *(const v8bf*)(abase + kb * 64);
    }

    const int cq0 = q * 512;
    int dt[4], pt[4];
#pragma unroll
    for (int rf = 0; rf < 4; ++rf) {
        const int drow = wrbase + rf * 16;
        dt[rf] = (drow >= cq0 && drow < cq0 + 512) ? ((drow - cq0) >> 4) : -1;
        const int pcol = (drow + NHALF) & (TWO_N - 1);
        pt[rf] = (pcol >= cq0 && pcol < cq0 + 512) ? ((pcol - cq0) >> 4) : -1;
    }

    float sume[4][4];
#pragma unroll
    for (int rf = 0; rf < 4; ++rf)
#pragma unroll
        for (int j = 0; j < 4; ++j) sume[rf][j] = 0.0f;

#pragma unroll 2
    for (int t = 0; t < 32; ++t) {
        const char* bbase =
            znb + (((size_t)(cq0 + t * 16 + lrow)) << 9) + (lk << 4);
        v8bf bfrag[8];
#pragma unroll
        for (int kb = 0; kb < 8; ++kb)
            bfrag[kb] = *(const v8bf*)(bbase + kb * 64);

        f32x4 acc[4];
#pragma unroll
        for (int rf = 0; rf < 4; ++rf) acc[rf] = (f32x4){0.f, 0.f, 0.f, 0.f};
#pragma unroll
        for (int kb = 0; kb < 8; ++kb) {
#pragma unroll
            for (int rf = 0; rf < 4; ++rf)
                acc[rf] = __builtin_amdgcn_mfma_f32_16x16x32_bf16(
                    afrag[rf][kb], bfrag[kb], acc[rf], 0, 0, 0);
        }

#pragma unroll
        for (int rf = 0; rf < 4; ++rf) {
            const bool isd = (t == dt[rf]);   // wave-uniform
            const bool isp = (t == pt[rf]);   // wave-uniform
#pragma unroll
            for (int j = 0; j < 4; ++j) {
                const float s = acc[rf][j];
                const bool ondiag = (lrow == lk * 4 + j);
                if (isp && ondiag)
                    spos[wrbase + rf * 16 + lk * 4 + j] = s * INV_T;
                const float e = EXP2F(s * SCALE);
                sume[rf][j] += (isd && ondiag) ? 0.0f : e;
            }
        }
    }

    // reduce across the 16 columns (lanes sharing lk differ in bits 0..3)
#pragma unroll
    for (int rf = 0; rf < 4; ++rf) {
#pragma unroll
        for (int j = 0; j < 4; ++j) {
            float v = sume[rf][j];
            v += __shfl_xor(v, 1);
            v += __shfl_xor(v, 2);
            v += __shfl_xor(v, 4);
            v += __shfl_xor(v, 8);
            if (lrow == 0)
                partial[(size_t)q * TWO_N + wrbase + rf * 16 + lk * 4 + j] = v;
        }
    }
}

// ---------------- kernel 3: finalize (out zeroed by kernel 1) ----------------
__global__ __launch_bounds__(256) void ntx_final_kernel(
    const float* __restrict__ partial, const float* __restrict__ spos,
    float* __restrict__ out) {
    const int tid = threadIdx.x;
    const int r = blockIdx.x * 256 + tid;
    float se = 0.0f;
#pragma unroll
    for (int c = 0; c < NCHUNK; ++c) se += partial[(size_t)c * TWO_N + r];
    float nll = logf(se) - spos[r];
    __shared__ float red[256];
    red[tid] = nll;
    __syncthreads();
    for (int s = 128; s > 0; s >>= 1) {
        if (tid < s) red[tid] += red[tid + s];
        __syncthreads();
    }
    if (tid == 0) atomicAdd(out, red[0] * (1.0f / (float)TWO_N));
}

extern "C" void kernel_launch(void* const* d_in, const int* in_sizes, int n_in,
                              void* d_out, int out_size, void* d_ws, size_t ws_size,
                              hipStream_t stream) {
    const float* zi = (const float*)d_in[0];
    const float* zj = (const float*)d_in[1];
    char* ws = (char*)d_ws;
    __hip_bfloat16* zn = (__hip_bfloat16*)ws;                          // 4 MB
    size_t off = (size_t)TWO_N * DDIM * 2;
    float* partial = (float*)(ws + off);                               // 512 KB
    off += (size_t)NCHUNK * TWO_N * 4;
    float* spos = (float*)(ws + off);                                  // 32 KB
    float* out = (float*)d_out;

    ntx_norm_kernel<<<TWO_N / 4, 256, 0, stream>>>(zi, zj, zn, out);
    ntx_gram_kernel<<<512, 256, 0, stream>>>(zn, partial, spos);
    ntx_final_kernel<<<TWO_N / 256, 256, 0, stream>>>(partial, spos, out);
}